// Round 11
// baseline (279.795 us; speedup 1.0000x reference)
//
#include <hip/hip_runtime.h>
#include <hip/hip_bf16.h>

#define BATCH 8
#define TLEN 2048
#define PADR 256
#define XT_ROWS (TLEN + PADR + 64)     // 2368 rows (64 slack rows at tail)
#define GT_BYTES (2048*1024*2)         // Gt[2048][32][32] bf16 = 4 MiB
#define XT_BYTES (BATCH*XT_ROWS*32*2)
#define JOBS_PER_B 144                 // sum over J=0..7 of 4*(J+1)
#define NJOBS (BATCH*JOBS_PER_B)       // 1152

using short8 = __attribute__((ext_vector_type(8))) short;
using f32x4  = __attribute__((ext_vector_type(4))) float;

typedef __attribute__((address_space(3))) char lds_char;
typedef __attribute__((address_space(1))) const char g_char;
static __device__ __forceinline__ void gload16(const void* g, void* l) {
    __builtin_amdgcn_global_load_lds((g_char*)g, (lds_char*)l, 16, 0, 0);
}

// ---- K1 (fused): [0,256) SIREN net; [256,512) x transpose; [512,1024) seed out with bias --
__global__ __launch_bounds__(256) void prep_kernel(
        const float* __restrict__ pos, const float* __restrict__ w1,
        const float* __restrict__ b1, const float* __restrict__ w2,
        const float* __restrict__ b2, const float* __restrict__ w3,
        const float* __restrict__ b3, const float* __restrict__ x,
        const float* __restrict__ bias,
        __hip_bfloat16* __restrict__ Gt, __hip_bfloat16* __restrict__ xT,
        float* __restrict__ out) {
    __shared__ float ot[128][65];           // SIREN out-tile / transpose tile
    int tid = threadIdx.x;
    if (blockIdx.x < 256) {
        int dblk = blockIdx.x >> 3, oblk = blockIdx.x & 7;
        int l  = tid & 63;
        int wu = __builtin_amdgcn_readfirstlane(tid >> 6);   // wave id, provably uniform
        int d  = dblk*64 + l;
        float p = pos[2048 - d];
        float t1[32], h2[32];
        #pragma unroll
        for (int k = 0; k < 32; ++k) t1[k] = sinf(w1[k]*p + b1[k]);
        #pragma unroll
        for (int j = 0; j < 32; ++j) {       // fully unrolled: h2 stays in registers
            float s0 = 0.f, s1 = 0.f;
            #pragma unroll
            for (int k = 0; k < 16; ++k) {
                s0 += w2[j*32 + k]      * t1[k];
                s1 += w2[j*32 + 16 + k] * t1[16 + k];
            }
            h2[j] = sinf(b2[j] + s0 + s1);
        }
        int obase = oblk*128 + wu*32;
        for (int ji = 0; ji < 32; ++ji) {    // oi wave-uniform -> w3 via scalar loads
            int oi = obase + ji;
            float s0 = 0.f, s1 = 0.f;
            #pragma unroll
            for (int k = 0; k < 16; ++k) {
                s0 += w3[oi*32 + k]      * h2[k];
                s1 += w3[oi*32 + 16 + k] * h2[16 + k];
            }
            ot[wu*32 + ji][l] = b3[oi] + s0 + s1;
        }
        __syncthreads();
        #pragma unroll
        for (int it = 0; it < 32; ++it) {    // coalesced bf16 stores, conflict-free LDS reads
            int e  = it*256 + tid;
            int dl = e >> 7, jq = e & 127;
            Gt[(size_t)(dblk*64 + dl)*1024 + oblk*128 + jq] = __float2bfloat16(ot[jq][dl]);
        }
    } else if (blockIdx.x < 512) {
        int blk = blockIdx.x - 256;
        int b = blk >> 5;
        int c = blk & 31;
        int t0 = c * 64;
        #pragma unroll
        for (int r = 0; r < 8; ++r) {
            int i  = r*4 + (tid >> 6);
            int tl = tid & 63;
            ot[i][tl] = x[((size_t)(b*32 + i))*TLEN + t0 + tl];
        }
        __syncthreads();
        #pragma unroll
        for (int r = 0; r < 8; ++r) {
            int idx = r*256 + tid;
            int tl = idx >> 5, i = idx & 31;
            xT[((size_t)(b*XT_ROWS + PADR + t0 + tl))*32 + i] = __float2bfloat16(ot[i][tl]);
        }
        if (c == 0) {
            for (int idx = tid; idx < PADR*32; idx += 256)
                xT[(size_t)b*XT_ROWS*32 + idx] = __float2bfloat16(0.0f);
        }
        if (c == 1) {
            for (int idx = tid; idx < 64*32; idx += 256)
                xT[((size_t)b*XT_ROWS + PADR + TLEN)*32 + idx] = __float2bfloat16(0.0f);
        }
    } else {
        // seed out with bias (out is re-poisoned before every launch; conv atomically adds)
        int idx4 = (blockIdx.x - 512)*256 + tid;       // 131072 float4's
        int e    = idx4*4;
        int o    = (e >> 11) & 31;                     // 4-aligned e: same o for all 4 elems
        float bv = bias[o];
        f32x4 v = {bv, bv, bv, bv};
        *reinterpret_cast<f32x4*>(out + e) = v;
    }
}

// ---- K3: A in swizzled LDS; B double-buffered in LDS via global_load_lds, 8-d phases ------
#define MFMA8(A0,A1,A2,A3,B0,B1)                                                  \
    acc[0][0] = __builtin_amdgcn_mfma_f32_16x16x32_bf16(A0, B0, acc[0][0], 0,0,0); \
    acc[0][1] = __builtin_amdgcn_mfma_f32_16x16x32_bf16(A0, B1, acc[0][1], 0,0,0); \
    acc[1][0] = __builtin_amdgcn_mfma_f32_16x16x32_bf16(A1, B0, acc[1][0], 0,0,0); \
    acc[1][1] = __builtin_amdgcn_mfma_f32_16x16x32_bf16(A1, B1, acc[1][1], 0,0,0); \
    acc[2][0] = __builtin_amdgcn_mfma_f32_16x16x32_bf16(A2, B0, acc[2][0], 0,0,0); \
    acc[2][1] = __builtin_amdgcn_mfma_f32_16x16x32_bf16(A2, B1, acc[2][1], 0,0,0); \
    acc[3][0] = __builtin_amdgcn_mfma_f32_16x16x32_bf16(A3, B0, acc[3][0], 0,0,0); \
    acc[3][1] = __builtin_amdgcn_mfma_f32_16x16x32_bf16(A3, B1, acc[3][1], 0,0,0);

__global__ __launch_bounds__(256) void conv_mfma(const __hip_bfloat16* __restrict__ GtB,
                                                 const __hip_bfloat16* __restrict__ xTB,
                                                 float* __restrict__ out) {
    __shared__ short8 lds_a[320*4];        // 20 KB, slot-swizzled: slot' = slot ^ ((row>>1)&3)
    __shared__ short8 lds_b[2][1024];      // 2 x 16 KB (8 d x 2 KB each)
    int tid  = threadIdx.x;
    int lane = tid & 63;
    int wu   = __builtin_amdgcn_readfirstlane(tid >> 6);
    int jid  = blockIdx.x;
    int b    = jid / JOBS_PER_B;
    int r    = jid - b * JOBS_PER_B;
    int J = (int)((sqrtf(2.0f*r + 1.0f) - 1.0f) * 0.5f);
    while (2*(J+1)*(J+2) <= r) ++J;
    while (2*J*(J+1) > r) --J;
    int S  = r - 2*J*(J+1);
    int d0 = 64*S;

    const short8* xs = (const short8*)xTB;
    int g0 = b*XT_ROWS + PADR + 256*J - 64*S - 63;
    #pragma unroll
    for (int c = 0; c < 5; ++c) {          // stage A window (320 rows x 64 B), swizzled
        int lr   = c*64 + (tid >> 2);
        int slot = tid & 3;
        lds_a[lr*4 + (slot ^ ((lr >> 1) & 3))] = xs[(size_t)(g0 + lr)*4 + slot];
    }
    // stage B chunk 0 (d0..d0+8): 16 KB linear; wave wu stages its 4 KB quarter
    const char* gB = (const char*)GtB + (size_t)d0*2048;
    {
        const char* src = gB + wu*4096 + lane*16;
        char*       dst = (char*)(&lds_b[0][0]) + wu*4096;
        #pragma unroll
        for (int i = 0; i < 4; ++i) gload16(src + i*1024, dst + i*1024);
    }
    __syncthreads();

    int l15 = lane & 15, l4 = lane >> 4;
    int r0 = 63 + 64*wu + l15;             // LDS-local A row for d-offset 0

    f32x4 acc[4][2];
    const f32x4 zero = {0.f, 0.f, 0.f, 0.f};
    #pragma unroll
    for (int mt = 0; mt < 4; ++mt) { acc[mt][0] = zero; acc[mt][1] = zero; }

    for (int p = 0; p < 8; ++p) {
        if (p < 7) {                       // async-stage chunk p+1 into the other buffer
            const char* src = gB + (p+1)*16384 + wu*4096 + lane*16;
            char*       dst = (char*)(&lds_b[(p+1)&1][0]) + wu*4096;
            #pragma unroll
            for (int i = 0; i < 4; ++i) gload16(src + i*1024, dst + i*1024);
        }
        const short8* bb = &lds_b[p&1][0];
        #pragma unroll
        for (int q = 0; q < 8; ++q) {      // 8 d-steps from LDS only
            short8 bv0 = bb[q*128 + l15*4 + l4];
            short8 bv1 = bb[q*128 + l15*4 + l4 + 64];
            int ai = r0*4 + (l4 ^ ((r0 >> 1) & 3));
            short8 a0 = lds_a[ai], a1 = lds_a[ai+64], a2 = lds_a[ai+128], a3 = lds_a[ai+192];
            r0--;
            MFMA8(a0, a1, a2, a3, bv0, bv1)
        }
        __syncthreads();                   // drains staged loads (vmcnt) + phase sync
    }

    // atomic accumulate into out[b][o][256J + tl] (bias pre-seeded by prep)
    float* po = out + ((size_t)b*32)*TLEN + 256*J;
    #pragma unroll
    for (int no = 0; no < 2; ++no)
        #pragma unroll
        for (int mt = 0; mt < 4; ++mt) {
            int o  = 16*no + l15;
            int tl = 64*wu + 16*mt + l4*4;
            #pragma unroll
            for (int jj = 0; jj < 4; ++jj)
                atomicAdd(po + (size_t)o*TLEN + tl + jj, acc[mt][no][jj]);
        }
}

extern "C" void kernel_launch(void* const* d_in, const int* in_sizes, int n_in,
                              void* d_out, int out_size, void* d_ws, size_t ws_size,
                              hipStream_t stream) {
    const float* x    = (const float*)d_in[0];
    const float* pos  = (const float*)d_in[1];
    const float* w1   = (const float*)d_in[2];
    const float* b1   = (const float*)d_in[3];
    const float* w2   = (const float*)d_in[4];
    const float* b2   = (const float*)d_in[5];
    const float* w3   = (const float*)d_in[6];
    const float* b3   = (const float*)d_in[7];
    const float* bias = (const float*)d_in[8];
    float* out = (float*)d_out;

    char* ws = (char*)d_ws;
    __hip_bfloat16* Gt = (__hip_bfloat16*)ws;
    __hip_bfloat16* xT = (__hip_bfloat16*)(ws + GT_BYTES);

    hipLaunchKernelGGL(prep_kernel, dim3(1024), dim3(256), 0, stream,
                       pos, w1, b1, w2, b2, w3, b3, x, bias, Gt, xT, out);
    hipLaunchKernelGGL(conv_mfma,   dim3(NJOBS), dim3(256), 0, stream, Gt, xT, out);
}

// Round 13
// 146.964 us; speedup vs baseline: 1.9038x; 1.9038x over previous
//
#include <hip/hip_runtime.h>
#include <hip/hip_bf16.h>

#define BATCH 8
#define TLEN 2048
#define PADR 256
#define XT_ROWS (TLEN + PADR + 64)     // 2368 rows (64 slack rows at tail)
#define GT_BYTES (2048*1024*2)         // Gt[2048][32][32] bf16 = 4 MiB
#define XT_BYTES (BATCH*XT_ROWS*32*2)
#define PART_OFF ((GT_BYTES + XT_BYTES + 255) & ~255)
#define JOBS_PER_B 144                 // sum over J=0..7 of 4*(J+1)
#define NJOBS (BATCH*JOBS_PER_B)       // 1152

using short8 = __attribute__((ext_vector_type(8))) short;
using u16x4  = __attribute__((ext_vector_type(4))) unsigned short;
using f32x4  = __attribute__((ext_vector_type(4))) float;

typedef __attribute__((address_space(3))) char lds_char;
typedef __attribute__((address_space(1))) const char g_char;
static __device__ __forceinline__ void gload16(const void* g, void* l) {
    __builtin_amdgcn_global_load_lds((g_char*)g, (lds_char*)l, 16, 0, 0);
}
static __device__ __forceinline__ unsigned short f2bf_bits(float f) {
    __hip_bfloat16 h = __float2bfloat16(f);
    return __builtin_bit_cast(unsigned short, h);
}
static __device__ __forceinline__ float bf_bits2f(unsigned short u) {
    __hip_bfloat16 h = __builtin_bit_cast(__hip_bfloat16, u);
    return __bfloat162float(h);
}

// ---- K1 (fused): blocks [0,256) = SIREN net (thread=d, oi wave-uniform); [256,512) = transpose
__global__ __launch_bounds__(256) void prep_kernel(
        const float* __restrict__ pos, const float* __restrict__ w1,
        const float* __restrict__ b1, const float* __restrict__ w2,
        const float* __restrict__ b2, const float* __restrict__ w3,
        const float* __restrict__ b3, const float* __restrict__ x,
        __hip_bfloat16* __restrict__ Gt, __hip_bfloat16* __restrict__ xT) {
    __shared__ float ot[128][65];           // SIREN out-tile / transpose tile
    int tid = threadIdx.x;
    if (blockIdx.x < 256) {
        int dblk = blockIdx.x >> 3, oblk = blockIdx.x & 7;
        int l  = tid & 63;
        int wu = __builtin_amdgcn_readfirstlane(tid >> 6);   // wave id, provably uniform
        int d  = dblk*64 + l;
        float p = pos[2048 - d];
        float t1[32], h2[32];
        #pragma unroll
        for (int k = 0; k < 32; ++k) t1[k] = sinf(w1[k]*p + b1[k]);
        #pragma unroll
        for (int j = 0; j < 32; ++j) {       // fully unrolled: h2 stays in registers
            float s0 = 0.f, s1 = 0.f;
            #pragma unroll
            for (int k = 0; k < 16; ++k) {
                s0 += w2[j*32 + k]      * t1[k];
                s1 += w2[j*32 + 16 + k] * t1[16 + k];
            }
            h2[j] = sinf(b2[j] + s0 + s1);
        }
        int obase = oblk*128 + wu*32;
        for (int ji = 0; ji < 32; ++ji) {    // oi wave-uniform -> w3 via scalar loads
            int oi = obase + ji;
            float s0 = 0.f, s1 = 0.f;
            #pragma unroll
            for (int k = 0; k < 16; ++k) {
                s0 += w3[oi*32 + k]      * h2[k];
                s1 += w3[oi*32 + 16 + k] * h2[16 + k];
            }
            ot[wu*32 + ji][l] = b3[oi] + s0 + s1;
        }
        __syncthreads();
        #pragma unroll
        for (int it = 0; it < 32; ++it) {    // coalesced bf16 stores, conflict-free LDS reads
            int e  = it*256 + tid;
            int dl = e >> 7, jq = e & 127;
            Gt[(size_t)(dblk*64 + dl)*1024 + oblk*128 + jq] = __float2bfloat16(ot[jq][dl]);
        }
    } else {
        int blk = blockIdx.x - 256;
        int b = blk >> 5;
        int c = blk & 31;
        int t0 = c * 64;
        #pragma unroll
        for (int r = 0; r < 8; ++r) {
            int i  = r*4 + (tid >> 6);
            int tl = tid & 63;
            ot[i][tl] = x[((size_t)(b*32 + i))*TLEN + t0 + tl];
        }
        __syncthreads();
        #pragma unroll
        for (int r = 0; r < 8; ++r) {
            int idx = r*256 + tid;
            int tl = idx >> 5, i = idx & 31;
            xT[((size_t)(b*XT_ROWS + PADR + t0 + tl))*32 + i] = __float2bfloat16(ot[i][tl]);
        }
        if (c == 0) {
            for (int idx = tid; idx < PADR*32; idx += 256)
                xT[(size_t)b*XT_ROWS*32 + idx] = __float2bfloat16(0.0f);
        }
        if (c == 1) {
            for (int idx = tid; idx < 64*32; idx += 256)
                xT[((size_t)b*XT_ROWS + PADR + TLEN)*32 + idx] = __float2bfloat16(0.0f);
        }
    }
}

// ---- K3: A in swizzled LDS; B double-buffered in LDS via global_load_lds, 8-d phases ------
#define MFMA8(A0,A1,A2,A3,B0,B1)                                                  \
    acc[0][0] = __builtin_amdgcn_mfma_f32_16x16x32_bf16(A0, B0, acc[0][0], 0,0,0); \
    acc[0][1] = __builtin_amdgcn_mfma_f32_16x16x32_bf16(A0, B1, acc[0][1], 0,0,0); \
    acc[1][0] = __builtin_amdgcn_mfma_f32_16x16x32_bf16(A1, B0, acc[1][0], 0,0,0); \
    acc[1][1] = __builtin_amdgcn_mfma_f32_16x16x32_bf16(A1, B1, acc[1][1], 0,0,0); \
    acc[2][0] = __builtin_amdgcn_mfma_f32_16x16x32_bf16(A2, B0, acc[2][0], 0,0,0); \
    acc[2][1] = __builtin_amdgcn_mfma_f32_16x16x32_bf16(A2, B1, acc[2][1], 0,0,0); \
    acc[3][0] = __builtin_amdgcn_mfma_f32_16x16x32_bf16(A3, B0, acc[3][0], 0,0,0); \
    acc[3][1] = __builtin_amdgcn_mfma_f32_16x16x32_bf16(A3, B1, acc[3][1], 0,0,0);

__global__ __launch_bounds__(256) void conv_mfma(const __hip_bfloat16* __restrict__ GtB,
                                                 const __hip_bfloat16* __restrict__ xTB,
                                                 __hip_bfloat16* __restrict__ partial) {
    __shared__ short8 lds_a[320*4];        // 20 KB, slot-swizzled: slot' = slot ^ ((row>>1)&3)
    __shared__ short8 lds_b[2][1024];      // 2 x 16 KB (8 d x 2 KB each)
    int tid  = threadIdx.x;
    int lane = tid & 63;
    int wu   = __builtin_amdgcn_readfirstlane(tid >> 6);
    int jid  = blockIdx.x;
    int b    = jid / JOBS_PER_B;
    int r    = jid - b * JOBS_PER_B;
    int J = (int)((sqrtf(2.0f*r + 1.0f) - 1.0f) * 0.5f);
    while (2*(J+1)*(J+2) <= r) ++J;
    while (2*J*(J+1) > r) --J;
    int S  = r - 2*J*(J+1);
    int d0 = 64*S;

    const short8* xs = (const short8*)xTB;
    int g0 = b*XT_ROWS + PADR + 256*J - 64*S - 63;
    #pragma unroll
    for (int c = 0; c < 5; ++c) {          // stage A window (320 rows x 64 B), swizzled
        int lr   = c*64 + (tid >> 2);
        int slot = tid & 3;
        lds_a[lr*4 + (slot ^ ((lr >> 1) & 3))] = xs[(size_t)(g0 + lr)*4 + slot];
    }
    // stage B chunk 0 (d0..d0+8): 16 KB linear; wave wu stages its 4 KB quarter
    const char* gB = (const char*)GtB + (size_t)d0*2048;
    {
        const char* src = gB + wu*4096 + lane*16;
        char*       dst = (char*)(&lds_b[0][0]) + wu*4096;
        #pragma unroll
        for (int i = 0; i < 4; ++i) gload16(src + i*1024, dst + i*1024);
    }
    __syncthreads();

    int l15 = lane & 15, l4 = lane >> 4;
    int r0 = 63 + 64*wu + l15;             // LDS-local A row for d-offset 0

    f32x4 acc[4][2];
    const f32x4 zero = {0.f, 0.f, 0.f, 0.f};
    #pragma unroll
    for (int mt = 0; mt < 4; ++mt) { acc[mt][0] = zero; acc[mt][1] = zero; }

    for (int p = 0; p < 8; ++p) {
        if (p < 7) {                       // async-stage chunk p+1 into the other buffer
            const char* src = gB + (p+1)*16384 + wu*4096 + lane*16;
            char*       dst = (char*)(&lds_b[(p+1)&1][0]) + wu*4096;
            #pragma unroll
            for (int i = 0; i < 4; ++i) gload16(src + i*1024, dst + i*1024);
        }
        const short8* bb = &lds_b[p&1][0];
        #pragma unroll
        for (int q = 0; q < 8; ++q) {      // 8 d-steps from LDS only
            short8 bv0 = bb[q*128 + l15*4 + l4];
            short8 bv1 = bb[q*128 + l15*4 + l4 + 64];
            int ai = r0*4 + (l4 ^ ((r0 >> 1) & 3));
            short8 a0 = lds_a[ai], a1 = lds_a[ai+64], a2 = lds_a[ai+128], a3 = lds_a[ai+192];
            r0--;
            MFMA8(a0, a1, a2, a3, bv0, bv1)
        }
        __syncthreads();                   // drains staged loads (vmcnt) + phase sync
    }

    // partial[jid][o][t_local] in bf16 (halves the HBM round-trip vs f32)
    __hip_bfloat16* pw = partial + (size_t)jid * 8192;
    #pragma unroll
    for (int no = 0; no < 2; ++no)
        #pragma unroll
        for (int mt = 0; mt < 4; ++mt) {
            int addr = (16*no + l15)*256 + 64*wu + 16*mt + l4*4;
            u16x4 v;
            #pragma unroll
            for (int jj = 0; jj < 4; ++jj)
                v[jj] = f2bf_bits(acc[mt][no][jj]);
            *reinterpret_cast<u16x4*>(pw + addr) = v;
        }
}

// ---- K4: sum 4*(J+1) bf16 segments per (b,J) t-block, add bias, f32 out -------------------
__global__ void reduce_out(const __hip_bfloat16* __restrict__ partial,
                           const float* __restrict__ bias, float* __restrict__ out) {
    int gid = blockIdx.x * 256 + threadIdx.x;      // 131072 threads x 4 elems
    int tl4 = gid & 63;                            // group of 4 t's
    int J   = (gid >> 6) & 7;
    int o   = (gid >> 9) & 31;
    int b   = gid >> 14;
    int jid = b*JOBS_PER_B + 2*J*(J+1);
    int cnt = 4*(J+1);                              // multiple of 4
    const u16x4* p = (const u16x4*)(partial) + (size_t)jid*2048 + o*64 + tl4;
    f32x4 s0 = {0,0,0,0}, s1 = {0,0,0,0}, s2 = {0,0,0,0}, s3 = {0,0,0,0};
    for (int sg = 0; sg < cnt; sg += 4) {
        u16x4 v0 = p[(size_t)sg*2048],     v1 = p[(size_t)(sg+1)*2048];
        u16x4 v2 = p[(size_t)(sg+2)*2048], v3 = p[(size_t)(sg+3)*2048];
        #pragma unroll
        for (int jj = 0; jj < 4; ++jj) {
            s0[jj] += bf_bits2f(v0[jj]);
            s1[jj] += bf_bits2f(v1[jj]);
            s2[jj] += bf_bits2f(v2[jj]);
            s3[jj] += bf_bits2f(v3[jj]);
        }
    }
    float bv = bias[o];
    f32x4 res;
    #pragma unroll
    for (int jj = 0; jj < 4; ++jj) res[jj] = bv + ((s0[jj] + s1[jj]) + (s2[jj] + s3[jj]));
    *reinterpret_cast<f32x4*>(out + ((size_t)(b*32 + o))*TLEN + 256*J + tl4*4) = res;
}

extern "C" void kernel_launch(void* const* d_in, const int* in_sizes, int n_in,
                              void* d_out, int out_size, void* d_ws, size_t ws_size,
                              hipStream_t stream) {
    const float* x    = (const float*)d_in[0];
    const float* pos  = (const float*)d_in[1];
    const float* w1   = (const float*)d_in[2];
    const float* b1   = (const float*)d_in[3];
    const float* w2   = (const float*)d_in[4];
    const float* b2   = (const float*)d_in[5];
    const float* w3   = (const float*)d_in[6];
    const float* b3   = (const float*)d_in[7];
    const float* bias = (const float*)d_in[8];
    float* out = (float*)d_out;

    char* ws = (char*)d_ws;
    __hip_bfloat16* Gt = (__hip_bfloat16*)ws;
    __hip_bfloat16* xT = (__hip_bfloat16*)(ws + GT_BYTES);
    __hip_bfloat16* partial = (__hip_bfloat16*)(ws + PART_OFF);

    hipLaunchKernelGGL(prep_kernel, dim3(512),   dim3(256), 0, stream,
                       pos, w1, b1, w2, b2, w3, b3, x, Gt, xT);
    hipLaunchKernelGGL(conv_mfma,   dim3(NJOBS), dim3(256), 0, stream, Gt, xT, partial);
    hipLaunchKernelGGL(reduce_out,  dim3(512),   dim3(256), 0, stream, partial, bias, out);
}